// Round 5
// baseline (23783.926 us; speedup 1.0000x reference)
//
#include <hip/hip_runtime.h>

// LSTM: I=512, H=2048, O=512, T=4096, batch=1, fp32.
// Phase 1: xz[T][4H] = input @ W_ih^T + (b_ih + b_hh)   (tiled fp32 GEMM)
// Phase 2: persistent plain-launch kernel (256 blocks = 256 CUs co-resident,
//          launch_bounds(256,1)), W_hh register/AGPR-resident.
//          R5: NO grid barrier at all. h values are self-validating:
//          each h[j] is a uint64 (tag<<32 | fp32 bits), double-buffered by
//          step parity. Consumers poll the slots they need until the tag
//          matches the step — data arrival IS the sync (one MALL round-trip
//          per step instead of h-store + flag-store + poll + h-load).
//          Overwrite safety: writing h_{t+2} into parity buffer requires
//          having read ALL of h_{t+1}, which requires every block to have
//          finished reading h_t — so no reader can still need the old value.
// Phase 3: out = W_lin @ h_T + b_lin (unpacks the tagged h words).

#define TSTEPS 4096
#define HDIM   2048
#define GDIM   8192   // 4H
#define IDIM   512
#define ODIM   512

#define XZ_BYTES ((size_t)TSTEPS * GDIM * sizeof(float))   // 128 MB

typedef unsigned long long u64;

__device__ __forceinline__ float sigmoidf_fast(float x) {
    return 1.0f / (1.0f + __expf(-x));
}
__device__ __forceinline__ float tanhf_fast(float x) {
    return 2.0f / (1.0f + __expf(-2.0f * x)) - 1.0f;
}

// ---------------------------------------------------------------------------
// Phase 1: C[4096][8192] = A[4096][512] * B[8192][512]^T + (bih+bhh)[n]
// 128x128 block tile, BK=16, 256 threads, 8x8 per thread.
// ---------------------------------------------------------------------------
__global__ __launch_bounds__(256) void xz_gemm(
    const float* __restrict__ A, const float* __restrict__ B,
    const float* __restrict__ bih, const float* __restrict__ bhh,
    float* __restrict__ C)
{
    __shared__ float As[16][132];
    __shared__ float Bs[16][132];

    const int tid = threadIdx.x;
    const int m0 = blockIdx.y * 128;
    const int n0 = blockIdx.x * 128;
    const int tx = tid & 15;        // n-direction
    const int ty = tid >> 4;        // m-direction

    const int lrow  = tid >> 1;          // 0..127
    const int kbase = (tid & 1) * 8;     // k offset 0 or 8

    float acc[8][8] = {};

    for (int k0 = 0; k0 < IDIM; k0 += 16) {
        const float4 av0 = *(const float4*)(A + (size_t)(m0 + lrow) * IDIM + k0 + kbase);
        const float4 av1 = *(const float4*)(A + (size_t)(m0 + lrow) * IDIM + k0 + kbase + 4);
        const float4 bv0 = *(const float4*)(B + (size_t)(n0 + lrow) * IDIM + k0 + kbase);
        const float4 bv1 = *(const float4*)(B + (size_t)(n0 + lrow) * IDIM + k0 + kbase + 4);

        __syncthreads();   // previous tile fully consumed
        As[kbase + 0][lrow] = av0.x; As[kbase + 1][lrow] = av0.y;
        As[kbase + 2][lrow] = av0.z; As[kbase + 3][lrow] = av0.w;
        As[kbase + 4][lrow] = av1.x; As[kbase + 5][lrow] = av1.y;
        As[kbase + 6][lrow] = av1.z; As[kbase + 7][lrow] = av1.w;
        Bs[kbase + 0][lrow] = bv0.x; Bs[kbase + 1][lrow] = bv0.y;
        Bs[kbase + 2][lrow] = bv0.z; Bs[kbase + 3][lrow] = bv0.w;
        Bs[kbase + 4][lrow] = bv1.x; Bs[kbase + 5][lrow] = bv1.y;
        Bs[kbase + 6][lrow] = bv1.z; Bs[kbase + 7][lrow] = bv1.w;
        __syncthreads();

#pragma unroll
        for (int kk = 0; kk < 16; ++kk) {
            const float4 a0 = *(const float4*)&As[kk][ty * 8];
            const float4 a1 = *(const float4*)&As[kk][ty * 8 + 4];
            const float4 b0 = *(const float4*)&Bs[kk][tx * 8];
            const float4 b1 = *(const float4*)&Bs[kk][tx * 8 + 4];
            const float ar[8] = {a0.x, a0.y, a0.z, a0.w, a1.x, a1.y, a1.z, a1.w};
            const float br[8] = {b0.x, b0.y, b0.z, b0.w, b1.x, b1.y, b1.z, b1.w};
#pragma unroll
            for (int i = 0; i < 8; ++i)
#pragma unroll
                for (int jj = 0; jj < 8; ++jj)
                    acc[i][jj] = fmaf(ar[i], br[jj], acc[i][jj]);
        }
    }

    float bias[8];
#pragma unroll
    for (int jj = 0; jj < 8; ++jj) {
        const int n = n0 + tx * 8 + jj;
        bias[jj] = bih[n] + bhh[n];
    }
#pragma unroll
    for (int i = 0; i < 8; ++i) {
        float* crow = C + (size_t)(m0 + ty * 8 + i) * GDIM + n0 + tx * 8;
        float4 v0, v1;
        v0.x = acc[i][0] + bias[0]; v0.y = acc[i][1] + bias[1];
        v0.z = acc[i][2] + bias[2]; v0.w = acc[i][3] + bias[3];
        v1.x = acc[i][4] + bias[4]; v1.y = acc[i][5] + bias[5];
        v1.z = acc[i][6] + bias[6]; v1.w = acc[i][7] + bias[7];
        ((float4*)crow)[0] = v0;
        ((float4*)crow)[1] = v1;
    }
}

// ---------------------------------------------------------------------------
// Phase 2: persistent recurrent kernel. 256 blocks x 256 threads, plain
// launch (co-resident at 1 block/CU, launch_bounds(256,1)).
// tid -> j = tid>>5 (h index), gate = (tid>>3)&3 (i,f,g,o), chunk = tid&7.
// Each lane: 256 W_hh weights (64 float4, AGPR-resident) for row = g*H + j,
// k in [chunk*256, chunk*256+256). Owner lane (tid%32==0) holds c_j.
// hq: u64[2][2048] tagged h slots (tag<<32 | bits), parity = t&1, tag = t.
// ---------------------------------------------------------------------------
__global__ __launch_bounds__(256, 1) void lstm_rec(
    const float* __restrict__ Whh, const float* __restrict__ xz,
    u64* __restrict__ hq)
{
    // h staged per-step: chunk c at hsh[c*260 .. c*260+256), +4 skew per chunk
    // so matvec ds_read_b128 (8 distinct addrs) is bank-conflict-free.
    __shared__ float hsh[8 * 260];

    const int tidb = threadIdx.x;
    const int tid  = blockIdx.x * 256 + tidb;
    const int j    = tid >> 5;
    const int g    = (tid >> 3) & 3;
    const int ck   = tid & 7;
    const int row  = g * HDIM + j;
    const int wv   = tidb >> 6;    // wave 0..3
    const int ln   = tidb & 63;    // lane

    // one-time weight load into registers/AGPRs (64 MB total across grid)
    const float4* wsrc = (const float4*)(Whh + (size_t)row * HDIM + ck * 256);
    float4 w[64];
#pragma unroll
    for (int i = 0; i < 64; ++i) w[i] = wsrc[i];

    const bool owner = (tid & 31) == 0;
    float cstate = 0.0f;

    // this thread's 8 staging slots (k indices), fixed across steps
    int kk0[8];
#pragma unroll
    for (int m = 0; m < 8; ++m) kk0[m] = wv * 512 + m * 64 + ln;

    float zx = xz[row];   // xz[0][row]

    for (int t = 0; t < TSTEPS; ++t) {
        // ---- poll tagged h_t slots (coalesced agent-scope u64 loads) ----
        const u64* hsrc = hq + ((size_t)(t & 1) << 11);
        const unsigned tagexp = (unsigned)t;
        u64 v[8];
#pragma unroll
        for (int m = 0; m < 8; ++m)
            v[m] = __hip_atomic_load(hsrc + kk0[m], __ATOMIC_RELAXED,
                                     __HIP_MEMORY_SCOPE_AGENT);
        {
            unsigned spins = 0;
            for (;;) {
                bool ok = true;
#pragma unroll
                for (int m = 0; m < 8; ++m)
                    ok &= ((unsigned)(v[m] >> 32) == tagexp);
                if (ok) break;
#pragma unroll
                for (int m = 0; m < 8; ++m)
                    if ((unsigned)(v[m] >> 32) != tagexp)
                        v[m] = __hip_atomic_load(hsrc + kk0[m], __ATOMIC_RELAXED,
                                                 __HIP_MEMORY_SCOPE_AGENT);
                if (++spins > (1u << 22)) break;   // fail fast, no hang
            }
        }

        __syncthreads();   // all waves done reading hsh from previous step
#pragma unroll
        for (int m = 0; m < 8; ++m) {
            const int k = kk0[m];
            hsh[(k >> 8) * 260 + (k & 255)] = __uint_as_float((unsigned)v[m]);
        }
        __syncthreads();   // staging visible to all waves

        // ---- matvec from LDS (conflict-free b128 reads) ----
        const float4* hr = (const float4*)(hsh + ck * 260);
        float a0 = 0.f, a1 = 0.f, a2 = 0.f, a3 = 0.f;
#pragma unroll
        for (int i = 0; i < 64; ++i) {
            const float4 h4 = hr[i];
            a0 = fmaf(w[i].x, h4.x, a0);
            a1 = fmaf(w[i].y, h4.y, a1);
            a2 = fmaf(w[i].z, h4.z, a2);
            a3 = fmaf(w[i].w, h4.w, a3);
        }
        float d = (a0 + a1) + (a2 + a3);
        d += __shfl_xor(d, 1);
        d += __shfl_xor(d, 2);
        d += __shfl_xor(d, 4);
        const float z  = d + zx;
        const float zf = __shfl_xor(z, 8);    // gate f partner
        const float zg = __shfl_xor(z, 16);   // gate g partner
        const float zo = __shfl_xor(z, 24);   // gate o partner

        if (owner) {   // lane has (i,f,g,o) for its j in (z, zf, zg, zo)
            const float ig = sigmoidf_fast(z);
            const float fg = sigmoidf_fast(zf);
            const float gg = tanhf_fast(zg);
            const float og = sigmoidf_fast(zo);
            cstate = fmaf(fg, cstate, ig * gg);
            const float hval = og * tanhf_fast(cstate);
            const u64 pack = ((u64)(unsigned)(t + 1) << 32) |
                             (u64)__float_as_uint(hval);
            // publish h_{t+1}[j]: data + tag in one MALL write
            __hip_atomic_store(hq + ((size_t)((t + 1) & 1) << 11) + j, pack,
                               __ATOMIC_RELAXED, __HIP_MEMORY_SCOPE_AGENT);
        }

        // prefetch next xz row (read-only, normal cached load)
        const int tn = (t + 1 < TSTEPS) ? (t + 1) : (TSTEPS - 1);
        zx = xz[(size_t)tn * GDIM + row];
    }
}

// ---------------------------------------------------------------------------
// Phase 3: out[512] = W_lin[512][2048] @ h_T + b_lin. One wave per output.
// h_T = h_4096 lives in hq parity 0, packed (tag 4096 in high bits).
// ---------------------------------------------------------------------------
__global__ __launch_bounds__(256) void final_linear(
    const float* __restrict__ Wlin, const float* __restrict__ blin,
    const u64* __restrict__ hq, float* __restrict__ out)
{
    const int wid  = (blockIdx.x * 256 + threadIdx.x) >> 6;   // 0..511
    const int lane = threadIdx.x & 63;
    const float4* wr = (const float4*)(Wlin + (size_t)wid * HDIM);
    float acc = 0.f;
#pragma unroll
    for (int i = 0; i < 8; ++i) {
        const int f = (lane + 64 * i) * 4;       // float index base
        const float4 w4 = wr[lane + 64 * i];
        const float hx = __uint_as_float((unsigned)hq[f + 0]);
        const float hy = __uint_as_float((unsigned)hq[f + 1]);
        const float hz = __uint_as_float((unsigned)hq[f + 2]);
        const float hw = __uint_as_float((unsigned)hq[f + 3]);
        acc += w4.x * hx + w4.y * hy + w4.z * hz + w4.w * hw;
    }
#pragma unroll
    for (int off = 32; off > 0; off >>= 1) acc += __shfl_down(acc, off);
    if (lane == 0) out[wid] = acc + blin[wid];
}

extern "C" void kernel_launch(void* const* d_in, const int* in_sizes, int n_in,
                              void* d_out, int out_size, void* d_ws, size_t ws_size,
                              hipStream_t stream) {
    const float* input = (const float*)d_in[0];   // [4096][512]
    const float* Wih   = (const float*)d_in[1];   // [8192][512]
    const float* Whh   = (const float*)d_in[2];   // [8192][2048]
    const float* bih   = (const float*)d_in[3];   // [8192]
    const float* bhh   = (const float*)d_in[4];   // [8192]
    const float* Wlin  = (const float*)d_in[5];   // [512][2048]
    const float* blin  = (const float*)d_in[6];   // [512]
    float* out = (float*)d_out;                   // [512]

    char* ws = (char*)d_ws;
    float* xz = (float*)ws;                          // 128 MB
    u64*   hq = (u64*)(ws + XZ_BYTES);               // 2 x 2048 x 8 B = 32 KB

    // zero tagged h buffers: tag 0 + h=0.0f == valid h_0 (ws poisoned 0xAA)
    hipMemsetAsync(hq, 0, 2 * HDIM * sizeof(u64), stream);

    dim3 ggrid(GDIM / 128, TSTEPS / 128);   // (64, 32)
    xz_gemm<<<ggrid, 256, 0, stream>>>(input, Wih, bih, bhh, xz);

    // plain launch: 256 blocks, 1 block/CU => all co-resident on 256 CUs.
    lstm_rec<<<dim3(256), dim3(256), 0, stream>>>(Whh, xz, hq);

    final_linear<<<ODIM / 4, 256, 0, stream>>>(Wlin, blin, hq, out);
}